// Round 1
// baseline (1527.314 us; speedup 1.0000x reference)
//
#include <hip/hip_runtime.h>
#include <hip/hip_bf16.h>

#define HID 128
#define KIN 259   // 2*HID + 3

__device__ __forceinline__ void fma4(float (&acc)[4][4], int i, float a, float4 b) {
    acc[i][0] = fmaf(a, b.x, acc[i][0]);
    acc[i][1] = fmaf(a, b.y, acc[i][1]);
    acc[i][2] = fmaf(a, b.z, acc[i][2]);
    acc[i][3] = fmaf(a, b.w, acc[i][3]);
}

// ---------------- Edge kernel: messages + scatter-add ----------------
// 32 edges per block, 256 threads. Each thread computes a 4x4 output tile.
__global__ __launch_bounds__(256, 3)
void edge_kernel(const float* __restrict__ x,
                 const int*   __restrict__ ei,   // [2][E]
                 const float* __restrict__ ea,   // [E][3]
                 const float* __restrict__ Wm1,  // [259][128]
                 const float* __restrict__ bm1,
                 const float* __restrict__ Wm2,  // [128][128]
                 const float* __restrict__ bm2,
                 float* __restrict__ agg,        // [N][128]
                 int E)
{
    __shared__ alignas(16) float A[32][260];   // msg_in tile; later reused as H[32][128]
    __shared__ alignas(16) float Bs[32][128];  // weight K-chunk
    __shared__ int sdst[32];

    const int tid = threadIdx.x;
    const int e0  = blockIdx.x * 32;

    // ---- gather msg_in = [x[src] | x[dst] | edge_attr] ----
    const float4* x4 = (const float4*)x;
    float4* A4 = (float4*)&A[0][0];
    for (int idx = tid; idx < 32 * 65; idx += 256) {
        int r = idx / 65, c4 = idx % 65;
        int e = e0 + r;
        float4 v = make_float4(0.f, 0.f, 0.f, 0.f);
        if (e < E) {
            if (c4 < 32) {
                int s = ei[e];
                v = x4[(size_t)s * 32 + c4];
            } else if (c4 < 64) {
                int d = ei[E + e];
                v = x4[(size_t)d * 32 + (c4 - 32)];
            } else {
                v.x = ea[(size_t)e * 3 + 0];
                v.y = ea[(size_t)e * 3 + 1];
                v.z = ea[(size_t)e * 3 + 2];
                v.w = 0.f;
            }
        }
        A4[r * 65 + c4] = v;
    }
    if (tid < 32) {
        int e = e0 + tid;
        sdst[tid] = (e < E) ? ei[E + e] : -1;
    }
    __syncthreads();

    const int cg = tid & 31;   // cols cg*4 .. cg*4+3
    const int rg = tid >> 5;   // rows rg*4 .. rg*4+3
    const int r0 = rg * 4;

    float4* B4 = (float4*)&Bs[0][0];
    const float4* W1_4 = (const float4*)Wm1;

    // ---- GEMM1: [32,259] @ [259,128] ----
    float acc[4][4];
    #pragma unroll
    for (int i = 0; i < 4; ++i)
        #pragma unroll
        for (int j = 0; j < 4; ++j) acc[i][j] = 0.f;

    for (int k0 = 0; k0 < KIN; k0 += 32) {
        int kc = min(32, KIN - k0);
        for (int idx = tid; idx < kc * 32; idx += 256)
            B4[idx] = W1_4[k0 * 32 + idx];
        __syncthreads();
        if (kc == 32) {
            #pragma unroll 8
            for (int kk = 0; kk < 32; ++kk) {
                float4 b = B4[kk * 32 + cg];
                float a0 = A[r0 + 0][k0 + kk];
                float a1 = A[r0 + 1][k0 + kk];
                float a2 = A[r0 + 2][k0 + kk];
                float a3 = A[r0 + 3][k0 + kk];
                fma4(acc, 0, a0, b); fma4(acc, 1, a1, b);
                fma4(acc, 2, a2, b); fma4(acc, 3, a3, b);
            }
        } else {
            for (int kk = 0; kk < kc; ++kk) {
                float4 b = B4[kk * 32 + cg];
                float a0 = A[r0 + 0][k0 + kk];
                float a1 = A[r0 + 1][k0 + kk];
                float a2 = A[r0 + 2][k0 + kk];
                float a3 = A[r0 + 3][k0 + kk];
                fma4(acc, 0, a0, b); fma4(acc, 1, a1, b);
                fma4(acc, 2, a2, b); fma4(acc, 3, a3, b);
            }
        }
        __syncthreads();
    }

    // ---- h = relu(acc + b_msg1), store into A's storage as H[32][128] ----
    float* H = &A[0][0];
    float4* H4 = (float4*)H;
    {
        float4 bb = ((const float4*)bm1)[cg];
        #pragma unroll
        for (int i = 0; i < 4; ++i) {
            float4 hv;
            hv.x = fmaxf(acc[i][0] + bb.x, 0.f);
            hv.y = fmaxf(acc[i][1] + bb.y, 0.f);
            hv.z = fmaxf(acc[i][2] + bb.z, 0.f);
            hv.w = fmaxf(acc[i][3] + bb.w, 0.f);
            H4[(r0 + i) * 32 + cg] = hv;
        }
    }
    __syncthreads();

    // ---- GEMM2: H[32,128] @ [128,128] ----
    float acc2[4][4];
    #pragma unroll
    for (int i = 0; i < 4; ++i)
        #pragma unroll
        for (int j = 0; j < 4; ++j) acc2[i][j] = 0.f;

    const float4* W2_4 = (const float4*)Wm2;
    for (int k0 = 0; k0 < 128; k0 += 32) {
        for (int idx = tid; idx < 32 * 32; idx += 256)
            B4[idx] = W2_4[k0 * 32 + idx];
        __syncthreads();
        #pragma unroll 8
        for (int kk = 0; kk < 32; ++kk) {
            float4 b = B4[kk * 32 + cg];
            float a0 = H[(r0 + 0) * 128 + k0 + kk];
            float a1 = H[(r0 + 1) * 128 + k0 + kk];
            float a2 = H[(r0 + 2) * 128 + k0 + kk];
            float a3 = H[(r0 + 3) * 128 + k0 + kk];
            fma4(acc2, 0, a0, b); fma4(acc2, 1, a1, b);
            fma4(acc2, 2, a2, b); fma4(acc2, 3, a3, b);
        }
        __syncthreads();
    }

    // ---- messages = acc2 + b_msg2; atomic scatter-add into agg[dst] ----
    {
        float4 bb = ((const float4*)bm2)[cg];
        #pragma unroll
        for (int i = 0; i < 4; ++i) {
            int e = e0 + r0 + i;
            if (e >= E) continue;
            int d = sdst[r0 + i];
            float* p = agg + (size_t)d * 128 + cg * 4;
            unsafeAtomicAdd(p + 0, acc2[i][0] + bb.x);
            unsafeAtomicAdd(p + 1, acc2[i][1] + bb.y);
            unsafeAtomicAdd(p + 2, acc2[i][2] + bb.z);
            unsafeAtomicAdd(p + 3, acc2[i][3] + bb.w);
        }
    }
}

// ---------------- Node kernel: gate/update MLP + LayerNorm ----------------
__global__ __launch_bounds__(256, 2)
void node_kernel(const float* __restrict__ x,
                 const float* __restrict__ agg,
                 const float* __restrict__ Wg,  const float* __restrict__ bg,
                 const float* __restrict__ Wu1, const float* __restrict__ bu1,
                 const float* __restrict__ Wu2, const float* __restrict__ bu2,
                 const float* __restrict__ gamma, const float* __restrict__ beta,
                 float* __restrict__ out, int N)
{
    __shared__ alignas(16) float A[32][256];   // [x | agg]; out overwrites agg half
    __shared__ alignas(16) float Bs[32][128];
    __shared__ alignas(16) float G[32][128];
    __shared__ alignas(16) float U[32][128];

    const int tid = threadIdx.x;
    const int n0  = blockIdx.x * 32;

    const float4* x4 = (const float4*)x;
    const float4* a4 = (const float4*)agg;
    float4* A4 = (float4*)&A[0][0];
    for (int idx = tid; idx < 32 * 64; idx += 256) {
        int r = idx >> 6, c4 = idx & 63;
        int n = n0 + r;
        float4 v = make_float4(0.f, 0.f, 0.f, 0.f);
        if (n < N) v = (c4 < 32) ? x4[(size_t)n * 32 + c4] : a4[(size_t)n * 32 + (c4 - 32)];
        A4[r * 64 + c4] = v;
    }
    __syncthreads();

    const int cg = tid & 31;
    const int rg = tid >> 5;
    const int r0 = rg * 4;

    float4* B4 = (float4*)&Bs[0][0];
    float4* G4 = (float4*)&G[0][0];
    float4* U4 = (float4*)&U[0][0];

    // ---- gate = sigmoid(A @ Wg + bg), K = 256 ----
    {
        float acc[4][4];
        #pragma unroll
        for (int i = 0; i < 4; ++i)
            #pragma unroll
            for (int j = 0; j < 4; ++j) acc[i][j] = 0.f;
        const float4* W4 = (const float4*)Wg;
        for (int k0 = 0; k0 < 256; k0 += 32) {
            for (int idx = tid; idx < 32 * 32; idx += 256)
                B4[idx] = W4[k0 * 32 + idx];
            __syncthreads();
            #pragma unroll 8
            for (int kk = 0; kk < 32; ++kk) {
                float4 b = B4[kk * 32 + cg];
                float a0 = A[r0 + 0][k0 + kk];
                float a1 = A[r0 + 1][k0 + kk];
                float a2 = A[r0 + 2][k0 + kk];
                float a3 = A[r0 + 3][k0 + kk];
                fma4(acc, 0, a0, b); fma4(acc, 1, a1, b);
                fma4(acc, 2, a2, b); fma4(acc, 3, a3, b);
            }
            __syncthreads();
        }
        float4 bb = ((const float4*)bg)[cg];
        #pragma unroll
        for (int i = 0; i < 4; ++i) {
            float4 g;
            g.x = 1.f / (1.f + expf(-(acc[i][0] + bb.x)));
            g.y = 1.f / (1.f + expf(-(acc[i][1] + bb.y)));
            g.z = 1.f / (1.f + expf(-(acc[i][2] + bb.z)));
            g.w = 1.f / (1.f + expf(-(acc[i][3] + bb.w)));
            G4[(r0 + i) * 32 + cg] = g;
        }
    }
    __syncthreads();

    // ---- u1 = relu(A @ Wu1 + bu1), K = 256 ----
    {
        float acc[4][4];
        #pragma unroll
        for (int i = 0; i < 4; ++i)
            #pragma unroll
            for (int j = 0; j < 4; ++j) acc[i][j] = 0.f;
        const float4* W4 = (const float4*)Wu1;
        for (int k0 = 0; k0 < 256; k0 += 32) {
            for (int idx = tid; idx < 32 * 32; idx += 256)
                B4[idx] = W4[k0 * 32 + idx];
            __syncthreads();
            #pragma unroll 8
            for (int kk = 0; kk < 32; ++kk) {
                float4 b = B4[kk * 32 + cg];
                float a0 = A[r0 + 0][k0 + kk];
                float a1 = A[r0 + 1][k0 + kk];
                float a2 = A[r0 + 2][k0 + kk];
                float a3 = A[r0 + 3][k0 + kk];
                fma4(acc, 0, a0, b); fma4(acc, 1, a1, b);
                fma4(acc, 2, a2, b); fma4(acc, 3, a3, b);
            }
            __syncthreads();
        }
        float4 bb = ((const float4*)bu1)[cg];
        #pragma unroll
        for (int i = 0; i < 4; ++i) {
            float4 u;
            u.x = fmaxf(acc[i][0] + bb.x, 0.f);
            u.y = fmaxf(acc[i][1] + bb.y, 0.f);
            u.z = fmaxf(acc[i][2] + bb.z, 0.f);
            u.w = fmaxf(acc[i][3] + bb.w, 0.f);
            U4[(r0 + i) * 32 + cg] = u;
        }
    }
    __syncthreads();

    // ---- u2 = U @ Wu2 + bu2; out = g*u2 + (1-g)*x -> store into A[:,128:256] ----
    {
        float acc[4][4];
        #pragma unroll
        for (int i = 0; i < 4; ++i)
            #pragma unroll
            for (int j = 0; j < 4; ++j) acc[i][j] = 0.f;
        const float4* W4 = (const float4*)Wu2;
        const float* Uf = &U[0][0];
        for (int k0 = 0; k0 < 128; k0 += 32) {
            for (int idx = tid; idx < 32 * 32; idx += 256)
                B4[idx] = W4[k0 * 32 + idx];
            __syncthreads();
            #pragma unroll 8
            for (int kk = 0; kk < 32; ++kk) {
                float4 b = B4[kk * 32 + cg];
                float a0 = Uf[(r0 + 0) * 128 + k0 + kk];
                float a1 = Uf[(r0 + 1) * 128 + k0 + kk];
                float a2 = Uf[(r0 + 2) * 128 + k0 + kk];
                float a3 = Uf[(r0 + 3) * 128 + k0 + kk];
                fma4(acc, 0, a0, b); fma4(acc, 1, a1, b);
                fma4(acc, 2, a2, b); fma4(acc, 3, a3, b);
            }
            __syncthreads();
        }
        float4 bb = ((const float4*)bu2)[cg];
        #pragma unroll
        for (int i = 0; i < 4; ++i) {
            float4 g  = G4[(r0 + i) * 32 + cg];
            float4 xv = A4[(r0 + i) * 64 + cg];
            float4 o;
            o.x = g.x * (acc[i][0] + bb.x) + (1.f - g.x) * xv.x;
            o.y = g.y * (acc[i][1] + bb.y) + (1.f - g.y) * xv.y;
            o.z = g.z * (acc[i][2] + bb.z) + (1.f - g.z) * xv.z;
            o.w = g.w * (acc[i][3] + bb.w) + (1.f - g.w) * xv.w;
            A4[(r0 + i) * 64 + 32 + cg] = o;   // out row r, overwrites agg half
        }
    }
    __syncthreads();

    // ---- LayerNorm over each row of 128, then store ----
    {
        const int w = tid >> 6;     // wave id 0..3
        const int lane = tid & 63;
        for (int rr = 0; rr < 8; ++rr) {
            int r = w * 8 + rr;
            int n = n0 + r;
            float v0 = A[r][128 + lane];
            float v1 = A[r][192 + lane];
            float s  = v0 + v1;
            float ss = v0 * v0 + v1 * v1;
            #pragma unroll
            for (int off = 32; off >= 1; off >>= 1) {
                s  += __shfl_xor(s,  off);
                ss += __shfl_xor(ss, off);
            }
            float mu   = s * (1.f / 128.f);
            float var  = ss * (1.f / 128.f) - mu * mu;
            float rstd = rsqrtf(var + 1e-5f);
            if (n < N) {
                out[(size_t)n * 128 + lane]      = (v0 - mu) * rstd * gamma[lane]      + beta[lane];
                out[(size_t)n * 128 + 64 + lane] = (v1 - mu) * rstd * gamma[64 + lane] + beta[64 + lane];
            }
        }
    }
}

extern "C" void kernel_launch(void* const* d_in, const int* in_sizes, int n_in,
                              void* d_out, int out_size, void* d_ws, size_t ws_size,
                              hipStream_t stream)
{
    const float* x    = (const float*)d_in[0];
    const int*   ei   = (const int*)  d_in[1];
    const float* ea   = (const float*)d_in[2];
    const float* Wm1  = (const float*)d_in[3];
    const float* bm1  = (const float*)d_in[4];
    const float* Wm2  = (const float*)d_in[5];
    const float* bm2  = (const float*)d_in[6];
    const float* Wg   = (const float*)d_in[7];
    const float* bg   = (const float*)d_in[8];
    const float* Wu1  = (const float*)d_in[9];
    const float* bu1  = (const float*)d_in[10];
    const float* Wu2  = (const float*)d_in[11];
    const float* bu2  = (const float*)d_in[12];
    const float* gmma = (const float*)d_in[13];
    const float* beta = (const float*)d_in[14];
    float* out = (float*)d_out;

    const int N = in_sizes[0] / HID;
    const int E = in_sizes[1] / 2;

    float* agg = (float*)d_ws;
    hipMemsetAsync(agg, 0, (size_t)N * HID * sizeof(float), stream);

    edge_kernel<<<dim3((E + 31) / 32), dim3(256), 0, stream>>>(
        x, ei, ea, Wm1, bm1, Wm2, bm2, agg, E);
    node_kernel<<<dim3((N + 31) / 32), dim3(256), 0, stream>>>(
        x, agg, Wg, bg, Wu1, bu1, Wu2, bu2, gmma, beta, out, N);
}

// Round 2
// 502.685 us; speedup vs baseline: 3.0383x; 3.0383x over previous
//
#include <hip/hip_runtime.h>
#include <hip/hip_bf16.h>

#define HID 128

typedef __attribute__((ext_vector_type(8))) short short8;
typedef __attribute__((ext_vector_type(4))) float f32x4;

__device__ __forceinline__ unsigned short f2bf(float f) {
    unsigned int u = __builtin_bit_cast(unsigned int, f);
    u += 0x7FFFu + ((u >> 16) & 1u);            // round-to-nearest-even
    return (unsigned short)(u >> 16);
}

__device__ __forceinline__ void fma4(float (&acc)[4][4], int i, float a, float4 b) {
    acc[i][0] = fmaf(a, b.x, acc[i][0]);
    acc[i][1] = fmaf(a, b.y, acc[i][1]);
    acc[i][2] = fmaf(a, b.z, acc[i][2]);
    acc[i][3] = fmaf(a, b.w, acc[i][3]);
}

// ---------------- prep: x -> bf16 ----------------
__global__ void prep_x(const float4* __restrict__ x4, unsigned short* __restrict__ xb, int n4) {
    int t = blockIdx.x * 256 + threadIdx.x;
    if (t >= n4) return;
    float4 v = x4[t];
    union { unsigned short u[4]; uint2 d; } p;
    p.u[0] = f2bf(v.x); p.u[1] = f2bf(v.y); p.u[2] = f2bf(v.z); p.u[3] = f2bf(v.w);
    *(uint2*)(xb + (size_t)t * 4) = p.d;
}

// ---------------- prep: W[k][128] -> fragment order Wf[ks][nt][lane][j] ----------------
// frag element j of lane: W[ks*32 + (lane>>4)*8 + j][nt*16 + (lane&15)]
__global__ void prep_w(const float* __restrict__ W, unsigned short* __restrict__ Wf, int nks) {
    int t = blockIdx.x * 256 + threadIdx.x;
    if (t >= nks * 8 * 64) return;
    int lane = t & 63, nt = (t >> 6) & 7, ks = t >> 9;
    int kb  = ks * 32 + ((lane >> 4) << 3);
    int col = (nt << 4) + (lane & 15);
    union { unsigned short u[8]; uint4 q; } p;
    #pragma unroll
    for (int j = 0; j < 8; ++j) p.u[j] = f2bf(W[(size_t)(kb + j) * 128 + col]);
    *(uint4*)(Wf + (size_t)t * 8) = p.q;
}

// ---------------- Edge kernel: bf16 MFMA messages + fp32 scatter-add ----------------
// 64 edges/block, 4 waves; each wave owns 16 edges (M=16), full N=128.
__global__ __launch_bounds__(256, 4)
void edge_mfma(const unsigned short* __restrict__ xb,   // [N][128] bf16
               const int* __restrict__ ei,              // [2][E]
               const float* __restrict__ ea,            // [E][3]
               const unsigned short* __restrict__ W1f,  // 8*8*64*8 bf16
               const unsigned short* __restrict__ W2f,  // 4*8*64*8 bf16
               const float* __restrict__ W1tail,        // W1 rows 256..258 [3][128] fp32
               const float* __restrict__ bm1,
               const float* __restrict__ bm2,
               float* __restrict__ agg,
               int E)
{
    __shared__ alignas(16) unsigned short As[4 * 4096]; // per wave: 16 rows x 512 B (swizzled)
    __shared__ float sW1e[3 * 128];
    __shared__ float sB1[128], sB2[128];
    __shared__ int   sIdx[4][32];   // [0:16) src, [16:32) dst
    __shared__ float sEA[4][48];

    const int tid  = threadIdx.x;
    const int lane = tid & 63;
    const int w    = tid >> 6;
    const int e0w  = blockIdx.x * 64 + w * 16;

    if (tid < 128) {
        sW1e[tid]       = W1tail[tid];
        sW1e[128 + tid] = W1tail[128 + tid];
        sW1e[256 + tid] = W1tail[256 + tid];
        sB1[tid] = bm1[tid];
        sB2[tid] = bm2[tid];
    }
    if (lane < 32) {
        int e = e0w + (lane & 15);
        sIdx[w][lane] = (e < E) ? ei[(lane < 16 ? 0 : E) + e] : 0;
    }
    if (lane < 48) {
        size_t b = (size_t)e0w * 3 + lane;
        sEA[w][lane] = (b < (size_t)E * 3) ? ea[b] : 0.f;
    }

    char* Aw = (char*)As + w * 8192;

    // gather [x_src | x_dst] bf16 rows into swizzled LDS (rows of 512 B; slot ^= row)
    #pragma unroll
    for (int it = 0; it < 8; ++it) {
        int g = it * 64 + lane;
        int r = g >> 4, c = g & 15;
        int e = r & 15, half = r >> 4;
        int node = sIdx[w][half * 16 + e];
        uint4 v = *(const uint4*)(xb + (size_t)node * 128 + c * 8);
        int b = half * 256 + c * 16;
        *(uint4*)(Aw + e * 512 + (b ^ (e << 4))) = v;
    }
    __syncthreads();

    const int arow = lane & 15;
    const int kgrp = (lane >> 4) << 4;   // byte offset of this lane's k-subgroup
    const int rbase = (lane >> 4) * 4;   // D-rows held by this lane

    // ---- GEMM1: [16,256]bf16 @ [256,128]bf16, fp32 acc ----
    f32x4 acc[8];
    #pragma unroll
    for (int i = 0; i < 8; ++i) acc[i] = (f32x4)0.f;

    #pragma unroll
    for (int ks = 0; ks < 8; ++ks) {
        short8 af = *(const short8*)(Aw + arow * 512 + ((ks * 64 + kgrp) ^ (arow << 4)));
        #pragma unroll
        for (int nt = 0; nt < 8; ++nt) {
            short8 bf = *(const short8*)(W1f + (size_t)((ks * 8 + nt) * 64 + lane) * 8);
            acc[nt] = __builtin_amdgcn_mfma_f32_16x16x32_bf16(af, bf, acc[nt], 0, 0, 0);
        }
    }

    // ---- epilogue 1: + edge_attr (exact fp32) + bias, relu, store H bf16 (swizzled, reuse A) ----
    float a0[4], a1[4], a2[4];
    #pragma unroll
    for (int r = 0; r < 4; ++r) {
        int e = rbase + r;
        a0[r] = sEA[w][e * 3 + 0];
        a1[r] = sEA[w][e * 3 + 1];
        a2[r] = sEA[w][e * 3 + 2];
    }
    #pragma unroll
    for (int nt = 0; nt < 8; ++nt) {
        int col = (nt << 4) + (lane & 15);
        float w0 = sW1e[col], w1 = sW1e[128 + col], w2 = sW1e[256 + col];
        float bb = sB1[col];
        #pragma unroll
        for (int r = 0; r < 4; ++r) {
            float h = acc[nt][r] + bb;
            h = fmaf(a0[r], w0, h);
            h = fmaf(a1[r], w1, h);
            h = fmaf(a2[r], w2, h);
            h = fmaxf(h, 0.f);
            int e = rbase + r;
            *(unsigned short*)(Aw + e * 256 + ((col * 2) ^ (e << 4))) = f2bf(h);
        }
    }
    __syncthreads();

    // ---- GEMM2: H[16,128]bf16 @ [128,128]bf16 ----
    #pragma unroll
    for (int i = 0; i < 8; ++i) acc[i] = (f32x4)0.f;
    #pragma unroll
    for (int ks = 0; ks < 4; ++ks) {
        short8 af = *(const short8*)(Aw + arow * 256 + ((ks * 64 + kgrp) ^ (arow << 4)));
        #pragma unroll
        for (int nt = 0; nt < 8; ++nt) {
            short8 bf = *(const short8*)(W2f + (size_t)((ks * 8 + nt) * 64 + lane) * 8);
            acc[nt] = __builtin_amdgcn_mfma_f32_16x16x32_bf16(af, bf, acc[nt], 0, 0, 0);
        }
    }

    // ---- epilogue 2: + bias, atomic scatter-add into agg[dst] ----
    #pragma unroll
    for (int nt = 0; nt < 8; ++nt) {
        int col = (nt << 4) + (lane & 15);
        float bb = sB2[col];
        #pragma unroll
        for (int r = 0; r < 4; ++r) {
            int e  = rbase + r;
            int eg = e0w + e;
            if (eg < E) {
                int d = sIdx[w][16 + e];
                unsafeAtomicAdd(agg + (size_t)d * 128 + col, acc[nt][r] + bb);
            }
        }
    }
}

// ---------------- Node kernel: gate/update MLP + LayerNorm (fp32, unchanged) ----------------
__global__ __launch_bounds__(256, 2)
void node_kernel(const float* __restrict__ x,
                 const float* __restrict__ agg,
                 const float* __restrict__ Wg,  const float* __restrict__ bg,
                 const float* __restrict__ Wu1, const float* __restrict__ bu1,
                 const float* __restrict__ Wu2, const float* __restrict__ bu2,
                 const float* __restrict__ gamma, const float* __restrict__ beta,
                 float* __restrict__ out, int N)
{
    __shared__ alignas(16) float A[32][256];
    __shared__ alignas(16) float Bs[32][128];
    __shared__ alignas(16) float G[32][128];
    __shared__ alignas(16) float U[32][128];

    const int tid = threadIdx.x;
    const int n0  = blockIdx.x * 32;

    const float4* x4 = (const float4*)x;
    const float4* a4 = (const float4*)agg;
    float4* A4 = (float4*)&A[0][0];
    for (int idx = tid; idx < 32 * 64; idx += 256) {
        int r = idx >> 6, c4 = idx & 63;
        int n = n0 + r;
        float4 v = make_float4(0.f, 0.f, 0.f, 0.f);
        if (n < N) v = (c4 < 32) ? x4[(size_t)n * 32 + c4] : a4[(size_t)n * 32 + (c4 - 32)];
        A4[r * 64 + c4] = v;
    }
    __syncthreads();

    const int cg = tid & 31;
    const int rg = tid >> 5;
    const int r0 = rg * 4;

    float4* B4 = (float4*)&Bs[0][0];
    float4* G4 = (float4*)&G[0][0];
    float4* U4 = (float4*)&U[0][0];

    { // gate
        float acc[4][4];
        #pragma unroll
        for (int i = 0; i < 4; ++i)
            #pragma unroll
            for (int j = 0; j < 4; ++j) acc[i][j] = 0.f;
        const float4* W4 = (const float4*)Wg;
        for (int k0 = 0; k0 < 256; k0 += 32) {
            for (int idx = tid; idx < 32 * 32; idx += 256)
                B4[idx] = W4[k0 * 32 + idx];
            __syncthreads();
            #pragma unroll 8
            for (int kk = 0; kk < 32; ++kk) {
                float4 b = B4[kk * 32 + cg];
                float v0 = A[r0 + 0][k0 + kk];
                float v1 = A[r0 + 1][k0 + kk];
                float v2 = A[r0 + 2][k0 + kk];
                float v3 = A[r0 + 3][k0 + kk];
                fma4(acc, 0, v0, b); fma4(acc, 1, v1, b);
                fma4(acc, 2, v2, b); fma4(acc, 3, v3, b);
            }
            __syncthreads();
        }
        float4 bb = ((const float4*)bg)[cg];
        #pragma unroll
        for (int i = 0; i < 4; ++i) {
            float4 g;
            g.x = 1.f / (1.f + expf(-(acc[i][0] + bb.x)));
            g.y = 1.f / (1.f + expf(-(acc[i][1] + bb.y)));
            g.z = 1.f / (1.f + expf(-(acc[i][2] + bb.z)));
            g.w = 1.f / (1.f + expf(-(acc[i][3] + bb.w)));
            G4[(r0 + i) * 32 + cg] = g;
        }
    }
    __syncthreads();

    { // u1 = relu(A @ Wu1 + bu1)
        float acc[4][4];
        #pragma unroll
        for (int i = 0; i < 4; ++i)
            #pragma unroll
            for (int j = 0; j < 4; ++j) acc[i][j] = 0.f;
        const float4* W4 = (const float4*)Wu1;
        for (int k0 = 0; k0 < 256; k0 += 32) {
            for (int idx = tid; idx < 32 * 32; idx += 256)
                B4[idx] = W4[k0 * 32 + idx];
            __syncthreads();
            #pragma unroll 8
            for (int kk = 0; kk < 32; ++kk) {
                float4 b = B4[kk * 32 + cg];
                float v0 = A[r0 + 0][k0 + kk];
                float v1 = A[r0 + 1][k0 + kk];
                float v2 = A[r0 + 2][k0 + kk];
                float v3 = A[r0 + 3][k0 + kk];
                fma4(acc, 0, v0, b); fma4(acc, 1, v1, b);
                fma4(acc, 2, v2, b); fma4(acc, 3, v3, b);
            }
            __syncthreads();
        }
        float4 bb = ((const float4*)bu1)[cg];
        #pragma unroll
        for (int i = 0; i < 4; ++i) {
            float4 u;
            u.x = fmaxf(acc[i][0] + bb.x, 0.f);
            u.y = fmaxf(acc[i][1] + bb.y, 0.f);
            u.z = fmaxf(acc[i][2] + bb.z, 0.f);
            u.w = fmaxf(acc[i][3] + bb.w, 0.f);
            U4[(r0 + i) * 32 + cg] = u;
        }
    }
    __syncthreads();

    { // u2 + gating
        float acc[4][4];
        #pragma unroll
        for (int i = 0; i < 4; ++i)
            #pragma unroll
            for (int j = 0; j < 4; ++j) acc[i][j] = 0.f;
        const float4* W4 = (const float4*)Wu2;
        const float* Uf = &U[0][0];
        for (int k0 = 0; k0 < 128; k0 += 32) {
            for (int idx = tid; idx < 32 * 32; idx += 256)
                B4[idx] = W4[k0 * 32 + idx];
            __syncthreads();
            #pragma unroll 8
            for (int kk = 0; kk < 32; ++kk) {
                float4 b = B4[kk * 32 + cg];
                float v0 = Uf[(r0 + 0) * 128 + k0 + kk];
                float v1 = Uf[(r0 + 1) * 128 + k0 + kk];
                float v2 = Uf[(r0 + 2) * 128 + k0 + kk];
                float v3 = Uf[(r0 + 3) * 128 + k0 + kk];
                fma4(acc, 0, v0, b); fma4(acc, 1, v1, b);
                fma4(acc, 2, v2, b); fma4(acc, 3, v3, b);
            }
            __syncthreads();
        }
        float4 bb = ((const float4*)bu2)[cg];
        #pragma unroll
        for (int i = 0; i < 4; ++i) {
            float4 g  = G4[(r0 + i) * 32 + cg];
            float4 xv = A4[(r0 + i) * 64 + cg];
            float4 o;
            o.x = g.x * (acc[i][0] + bb.x) + (1.f - g.x) * xv.x;
            o.y = g.y * (acc[i][1] + bb.y) + (1.f - g.y) * xv.y;
            o.z = g.z * (acc[i][2] + bb.z) + (1.f - g.z) * xv.z;
            o.w = g.w * (acc[i][3] + bb.w) + (1.f - g.w) * xv.w;
            A4[(r0 + i) * 64 + 32 + cg] = o;
        }
    }
    __syncthreads();

    { // LayerNorm
        const int w = tid >> 6;
        const int lane = tid & 63;
        for (int rr = 0; rr < 8; ++rr) {
            int r = w * 8 + rr;
            int n = n0 + r;
            float v0 = A[r][128 + lane];
            float v1 = A[r][192 + lane];
            float s  = v0 + v1;
            float ss = v0 * v0 + v1 * v1;
            #pragma unroll
            for (int off = 32; off >= 1; off >>= 1) {
                s  += __shfl_xor(s,  off);
                ss += __shfl_xor(ss, off);
            }
            float mu   = s * (1.f / 128.f);
            float var  = ss * (1.f / 128.f) - mu * mu;
            float rstd = rsqrtf(var + 1e-5f);
            if (n < N) {
                out[(size_t)n * 128 + lane]      = (v0 - mu) * rstd * gamma[lane]      + beta[lane];
                out[(size_t)n * 128 + 64 + lane] = (v1 - mu) * rstd * gamma[64 + lane] + beta[64 + lane];
            }
        }
    }
}

extern "C" void kernel_launch(void* const* d_in, const int* in_sizes, int n_in,
                              void* d_out, int out_size, void* d_ws, size_t ws_size,
                              hipStream_t stream)
{
    const float* x    = (const float*)d_in[0];
    const int*   ei   = (const int*)  d_in[1];
    const float* ea   = (const float*)d_in[2];
    const float* Wm1  = (const float*)d_in[3];
    const float* bm1  = (const float*)d_in[4];
    const float* Wm2  = (const float*)d_in[5];
    const float* bm2  = (const float*)d_in[6];
    const float* Wg   = (const float*)d_in[7];
    const float* bg   = (const float*)d_in[8];
    const float* Wu1  = (const float*)d_in[9];
    const float* bu1  = (const float*)d_in[10];
    const float* Wu2  = (const float*)d_in[11];
    const float* bu2  = (const float*)d_in[12];
    const float* gmma = (const float*)d_in[13];
    const float* beta = (const float*)d_in[14];
    float* out = (float*)d_out;

    const int N = in_sizes[0] / HID;
    const int E = in_sizes[1] / 2;

    // workspace carve-up
    float*          agg = (float*)d_ws;                         // N*128 f32
    unsigned short* xb  = (unsigned short*)(agg + (size_t)N * HID); // N*128 bf16
    unsigned short* W1f = xb + (size_t)N * HID;                 // 8*8*64*8 = 32768
    unsigned short* W2f = W1f + 32768;                          // 4*8*64*8 = 16384

    hipMemsetAsync(agg, 0, (size_t)N * HID * sizeof(float), stream);

    int n4 = N * HID / 4;
    prep_x<<<dim3((n4 + 255) / 256), dim3(256), 0, stream>>>((const float4*)x, xb, n4);
    prep_w<<<dim3(16), dim3(256), 0, stream>>>(Wm1, W1f, 8);
    prep_w<<<dim3(8),  dim3(256), 0, stream>>>(Wm2, W2f, 4);

    edge_mfma<<<dim3((E + 63) / 64), dim3(256), 0, stream>>>(
        xb, ei, ea, W1f, W2f, Wm1 + 256 * HID, bm1, bm2, agg, E);

    node_kernel<<<dim3((N + 31) / 32), dim3(256), 0, stream>>>(
        x, agg, Wg, bg, Wu1, bu1, Wu2, bu2, gmma, beta, out, N);
}

// Round 3
// 496.854 us; speedup vs baseline: 3.0740x; 1.0117x over previous
//
#include <hip/hip_runtime.h>
#include <hip/hip_bf16.h>

#define HID 128

typedef __attribute__((ext_vector_type(8))) short short8;
typedef __attribute__((ext_vector_type(4))) float f32x4;

__device__ __forceinline__ unsigned short f2bf(float f) {
    unsigned int u = __builtin_bit_cast(unsigned int, f);
    u += 0x7FFFu + ((u >> 16) & 1u);            // round-to-nearest-even
    return (unsigned short)(u >> 16);
}
__device__ __forceinline__ float bf2f(unsigned short h) {
    unsigned int u = ((unsigned int)h) << 16;
    return __builtin_bit_cast(float, u);
}

// ---------------- prep: x -> bf16 ----------------
__global__ void prep_x(const float4* __restrict__ x4, unsigned short* __restrict__ xb, int n4) {
    int t = blockIdx.x * 256 + threadIdx.x;
    if (t >= n4) return;
    float4 v = x4[t];
    union { unsigned short u[4]; uint2 d; } p;
    p.u[0] = f2bf(v.x); p.u[1] = f2bf(v.y); p.u[2] = f2bf(v.z); p.u[3] = f2bf(v.w);
    *(uint2*)(xb + (size_t)t * 4) = p.d;
}

// ---------------- prep: W[k][128] -> fragment order Wf[ks][nt][lane][j] ----------------
__global__ void prep_w(const float* __restrict__ W, unsigned short* __restrict__ Wf, int nks) {
    int t = blockIdx.x * 256 + threadIdx.x;
    if (t >= nks * 8 * 64) return;
    int lane = t & 63, nt = (t >> 6) & 7, ks = t >> 9;
    int kb  = ks * 32 + ((lane >> 4) << 3);
    int col = (nt << 4) + (lane & 15);
    union { unsigned short u[8]; uint4 q; } p;
    #pragma unroll
    for (int j = 0; j < 8; ++j) p.u[j] = f2bf(W[(size_t)(kb + j) * 128 + col]);
    *(uint4*)(Wf + (size_t)t * 8) = p.q;
}

// hi/lo split version for near-fp32 node GEMMs
__global__ void prep_w_split(const float* __restrict__ W,
                             unsigned short* __restrict__ Wh,
                             unsigned short* __restrict__ Wl, int nks) {
    int t = blockIdx.x * 256 + threadIdx.x;
    if (t >= nks * 8 * 64) return;
    int lane = t & 63, nt = (t >> 6) & 7, ks = t >> 9;
    int kb  = ks * 32 + ((lane >> 4) << 3);
    int col = (nt << 4) + (lane & 15);
    union { unsigned short u[8]; uint4 q; } ph, pl;
    #pragma unroll
    for (int j = 0; j < 8; ++j) {
        float w = W[(size_t)(kb + j) * 128 + col];
        unsigned short h = f2bf(w);
        ph.u[j] = h;
        pl.u[j] = f2bf(w - bf2f(h));
    }
    *(uint4*)(Wh + (size_t)t * 8) = ph.q;
    *(uint4*)(Wl + (size_t)t * 8) = pl.q;
}

// ---------------- Edge kernel: barrier-free, direct-global A-frags, M=32/wave ----------------
__global__ __launch_bounds__(256, 4)
void edge_mfma(const unsigned short* __restrict__ xb,   // [N][128] bf16
               const int* __restrict__ ei,              // [2][E]
               const float* __restrict__ ea,            // [E][3]
               const unsigned short* __restrict__ W1f,  // [8][8][64][8] bf16
               const unsigned short* __restrict__ W2f,  // [4][8][64][8] bf16
               const float* __restrict__ W1tail,        // [3][128] fp32
               const float* __restrict__ bm1,
               const float* __restrict__ bm2,
               float* __restrict__ agg,
               int E)
{
    __shared__ int   sSrc[4][32], sDst[4][32];
    __shared__ float sEA[4][96];
    __shared__ alignas(16) char Hs[4][8192];   // per-wave H: 32 rows x 256 B, XOR-swizzled

    const int tid  = threadIdx.x;
    const int lane = tid & 63;
    const int wid  = tid >> 6;
    const int e0   = blockIdx.x * 128 + wid * 32;

    // wave-private index / edge-attr staging (no cross-wave sharing -> no barriers)
    if (lane < 32) {
        int e  = e0 + lane;
        int ec = (e < E) ? e : (E - 1);
        sSrc[wid][lane] = ei[ec];
        sDst[wid][lane] = ei[E + ec];
    }
    {
        size_t b = (size_t)e0 * 3 + lane;
        sEA[wid][lane] = (b < (size_t)E * 3) ? ea[b] : 0.f;
        if (lane < 32) {
            size_t b2 = (size_t)e0 * 3 + 64 + lane;
            sEA[wid][64 + lane] = (b2 < (size_t)E * 3) ? ea[b2] : 0.f;
        }
    }

    const int arow = lane & 15;
    const int g4   = lane >> 4;

    // per-lane global A-frag base pointers (two row-groups x {src,dst})
    int s0 = sSrc[wid][arow],      s1 = sSrc[wid][16 + arow];
    int d0 = sDst[wid][arow],      d1 = sDst[wid][16 + arow];
    const unsigned short* pS0 = xb + (size_t)s0 * 128 + g4 * 8;
    const unsigned short* pS1 = xb + (size_t)s1 * 128 + g4 * 8;
    const unsigned short* pD0 = xb + (size_t)d0 * 128 + g4 * 8;
    const unsigned short* pD1 = xb + (size_t)d1 * 128 + g4 * 8;

    // ---- GEMM1: [32,256]bf16 @ [256,128]bf16 ----
    f32x4 acc0[8], acc1[8];
    #pragma unroll
    for (int i = 0; i < 8; ++i) { acc0[i] = (f32x4)0.f; acc1[i] = (f32x4)0.f; }

    #pragma unroll
    for (int ks = 0; ks < 8; ++ks) {
        short8 a0, a1;
        if (ks < 4) {
            a0 = *(const short8*)(pS0 + ks * 32);
            a1 = *(const short8*)(pS1 + ks * 32);
        } else {
            a0 = *(const short8*)(pD0 + (ks - 4) * 32);
            a1 = *(const short8*)(pD1 + (ks - 4) * 32);
        }
        #pragma unroll
        for (int nt = 0; nt < 8; ++nt) {
            short8 bf = *(const short8*)(W1f + (size_t)((ks * 8 + nt) * 64 + lane) * 8);
            acc0[nt] = __builtin_amdgcn_mfma_f32_16x16x32_bf16(a0, bf, acc0[nt], 0, 0, 0);
            acc1[nt] = __builtin_amdgcn_mfma_f32_16x16x32_bf16(a1, bf, acc1[nt], 0, 0, 0);
        }
    }

    // ---- epilogue 1: + edge_attr (exact fp32) + bias, relu, store H bf16 swizzled ----
    float eav[2][4][3];
    #pragma unroll
    for (int m = 0; m < 2; ++m)
        #pragma unroll
        for (int r = 0; r < 4; ++r) {
            int el = m * 16 + g4 * 4 + r;
            eav[m][r][0] = sEA[wid][el * 3 + 0];
            eav[m][r][1] = sEA[wid][el * 3 + 1];
            eav[m][r][2] = sEA[wid][el * 3 + 2];
        }

    #pragma unroll
    for (int nt = 0; nt < 8; ++nt) {
        int col = nt * 16 + arow;
        float w0 = W1tail[col], w1 = W1tail[128 + col], w2 = W1tail[256 + col];
        float b1 = bm1[col];
        #pragma unroll
        for (int m = 0; m < 2; ++m) {
            const f32x4& A = m ? acc1[nt] : acc0[nt];
            #pragma unroll
            for (int r = 0; r < 4; ++r) {
                int el = m * 16 + g4 * 4 + r;
                float h = A[r] + b1;
                h = fmaf(eav[m][r][0], w0, h);
                h = fmaf(eav[m][r][1], w1, h);
                h = fmaf(eav[m][r][2], w2, h);
                h = fmaxf(h, 0.f);
                *(unsigned short*)(&Hs[wid][el * 256 + ((col * 2) ^ ((el & 15) << 4))]) = f2bf(h);
            }
        }
    }

    // ---- GEMM2: H[32,128]bf16 @ [128,128]bf16 ----
    #pragma unroll
    for (int i = 0; i < 8; ++i) { acc0[i] = (f32x4)0.f; acc1[i] = (f32x4)0.f; }

    #pragma unroll
    for (int ks = 0; ks < 4; ++ks) {
        int b = ks * 64 + g4 * 16;
        short8 a0 = *(const short8*)(&Hs[wid][arow * 256        + (b ^ (arow << 4))]);
        short8 a1 = *(const short8*)(&Hs[wid][(16 + arow) * 256 + (b ^ (arow << 4))]);
        #pragma unroll
        for (int nt = 0; nt < 8; ++nt) {
            short8 bf = *(const short8*)(W2f + (size_t)((ks * 8 + nt) * 64 + lane) * 8);
            acc0[nt] = __builtin_amdgcn_mfma_f32_16x16x32_bf16(a0, bf, acc0[nt], 0, 0, 0);
            acc1[nt] = __builtin_amdgcn_mfma_f32_16x16x32_bf16(a1, bf, acc1[nt], 0, 0, 0);
        }
    }

    // ---- epilogue 2: + bias, atomic scatter-add into agg[dst] ----
    #pragma unroll
    for (int nt = 0; nt < 8; ++nt) {
        int col = nt * 16 + arow;
        float b2 = bm2[col];
        #pragma unroll
        for (int m = 0; m < 2; ++m) {
            const f32x4& A = m ? acc1[nt] : acc0[nt];
            #pragma unroll
            for (int r = 0; r < 4; ++r) {
                int el = m * 16 + g4 * 4 + r;
                int eg = e0 + el;
                if (eg < E) {
                    int d = sDst[wid][el];
                    unsafeAtomicAdd(agg + (size_t)d * 128 + col, A[r] + b2);
                }
            }
        }
    }
}

// ---------------- Node kernel: bf16 MFMA with hi/lo split (near-fp32) ----------------
__global__ __launch_bounds__(256, 3)
void node_mfma(const float* __restrict__ x,
               const float* __restrict__ agg,
               const unsigned short* __restrict__ WgH, const unsigned short* __restrict__ WgL,
               const unsigned short* __restrict__ Wu1H, const unsigned short* __restrict__ Wu1L,
               const unsigned short* __restrict__ Wu2H, const unsigned short* __restrict__ Wu2L,
               const float* __restrict__ bg, const float* __restrict__ bu1,
               const float* __restrict__ bu2,
               const float* __restrict__ gamma, const float* __restrict__ beta,
               float* __restrict__ out, int N)
{
    __shared__ alignas(16) char Hs[4][8192];   // per-wave u1 hi/lo packed: 16 rows x 512 B

    const int tid  = threadIdx.x;
    const int lane = tid & 63;
    const int wid  = tid >> 6;
    const int n0   = (blockIdx.x * 4 + wid) * 16;
    if (n0 >= N) return;

    const int arow = lane & 15;
    const int g4   = lane >> 4;

    int nr = n0 + arow; if (nr >= N) nr = N - 1;
    const float* px = x   + (size_t)nr * 128 + g4 * 8;
    const float* pa = agg + (size_t)nr * 128 + g4 * 8;

    // ---- build A-frags (hi/lo) for [x | agg], K = 256 ----
    short8 ah[8], al[8];
    #pragma unroll
    for (int ks = 0; ks < 8; ++ks) {
        const float* p = (ks < 4) ? (px + ks * 32) : (pa + (ks - 4) * 32);
        float4 v0 = *(const float4*)p;
        float4 v1 = *(const float4*)(p + 4);
        float v[8] = { v0.x, v0.y, v0.z, v0.w, v1.x, v1.y, v1.z, v1.w };
        #pragma unroll
        for (int j = 0; j < 8; ++j) {
            unsigned short h = f2bf(v[j]);
            ah[ks][j] = (short)h;
            al[ks][j] = (short)f2bf(v[j] - bf2f(h));
        }
    }

    // ---- gate GEMM (K=256, 3-pass split) ----
    f32x4 ga[8];
    #pragma unroll
    for (int i = 0; i < 8; ++i) ga[i] = (f32x4)0.f;
    #pragma unroll
    for (int ks = 0; ks < 8; ++ks) {
        #pragma unroll
        for (int nt = 0; nt < 8; ++nt) {
            size_t o = (size_t)((ks * 8 + nt) * 64 + lane) * 8;
            short8 bh = *(const short8*)(WgH + o);
            short8 bl = *(const short8*)(WgL + o);
            ga[nt] = __builtin_amdgcn_mfma_f32_16x16x32_bf16(ah[ks], bh, ga[nt], 0, 0, 0);
            ga[nt] = __builtin_amdgcn_mfma_f32_16x16x32_bf16(al[ks], bh, ga[nt], 0, 0, 0);
            ga[nt] = __builtin_amdgcn_mfma_f32_16x16x32_bf16(ah[ks], bl, ga[nt], 0, 0, 0);
        }
    }

    // ---- u1 GEMM (K=256, 3-pass split) ----
    f32x4 ua[8];
    #pragma unroll
    for (int i = 0; i < 8; ++i) ua[i] = (f32x4)0.f;
    #pragma unroll
    for (int ks = 0; ks < 8; ++ks) {
        #pragma unroll
        for (int nt = 0; nt < 8; ++nt) {
            size_t o = (size_t)((ks * 8 + nt) * 64 + lane) * 8;
            short8 bh = *(const short8*)(Wu1H + o);
            short8 bl = *(const short8*)(Wu1L + o);
            ua[nt] = __builtin_amdgcn_mfma_f32_16x16x32_bf16(ah[ks], bh, ua[nt], 0, 0, 0);
            ua[nt] = __builtin_amdgcn_mfma_f32_16x16x32_bf16(al[ks], bh, ua[nt], 0, 0, 0);
            ua[nt] = __builtin_amdgcn_mfma_f32_16x16x32_bf16(ah[ks], bl, ua[nt], 0, 0, 0);
        }
    }

    // relu + bias, split hi/lo, pack (hi|lo<<16) into wave-private LDS (transpose)
    #pragma unroll
    for (int nt = 0; nt < 8; ++nt) {
        int col = nt * 16 + arow;
        float b1 = bu1[col];
        #pragma unroll
        for (int r = 0; r < 4; ++r) {
            int row = g4 * 4 + r;
            float u = fmaxf(ua[nt][r] + b1, 0.f);
            unsigned short h = f2bf(u);
            unsigned short l = f2bf(u - bf2f(h));
            unsigned int pk = (unsigned int)h | ((unsigned int)l << 16);
            *(unsigned int*)(&Hs[wid][row * 512 + ((col * 4) ^ ((row & 15) << 4))]) = pk;
        }
    }

    // ---- gate finalize: sigmoid ----
    #pragma unroll
    for (int nt = 0; nt < 8; ++nt) {
        int col = nt * 16 + arow;
        float b = bg[col];
        #pragma unroll
        for (int r = 0; r < 4; ++r)
            ga[nt][r] = 1.f / (1.f + expf(-(ga[nt][r] + b)));
    }

    // ---- u2 GEMM (K=128, 3-pass split), A from LDS ----
    f32x4 u2[8];
    #pragma unroll
    for (int i = 0; i < 8; ++i) u2[i] = (f32x4)0.f;
    #pragma unroll
    for (int ks = 0; ks < 4; ++ks) {
        int b0 = ks * 128 + g4 * 32;
        unsigned int q0[4], q1[4];
        *(uint4*)q0 = *(const uint4*)(&Hs[wid][arow * 512 + ( b0       ^ (arow << 4))]);
        *(uint4*)q1 = *(const uint4*)(&Hs[wid][arow * 512 + ((b0 + 16) ^ (arow << 4))]);
        short8 a2h, a2l;
        #pragma unroll
        for (int j = 0; j < 4; ++j) {
            a2h[j]     = (short)(q0[j] & 0xffff);
            a2l[j]     = (short)(q0[j] >> 16);
            a2h[4 + j] = (short)(q1[j] & 0xffff);
            a2l[4 + j] = (short)(q1[j] >> 16);
        }
        #pragma unroll
        for (int nt = 0; nt < 8; ++nt) {
            size_t o = (size_t)((ks * 8 + nt) * 64 + lane) * 8;
            short8 bh = *(const short8*)(Wu2H + o);
            short8 bl = *(const short8*)(Wu2L + o);
            u2[nt] = __builtin_amdgcn_mfma_f32_16x16x32_bf16(a2h, bh, u2[nt], 0, 0, 0);
            u2[nt] = __builtin_amdgcn_mfma_f32_16x16x32_bf16(a2l, bh, u2[nt], 0, 0, 0);
            u2[nt] = __builtin_amdgcn_mfma_f32_16x16x32_bf16(a2h, bl, u2[nt], 0, 0, 0);
        }
    }

    // ---- epilogue: gating + LayerNorm + store ----
    float s[4]  = {0.f, 0.f, 0.f, 0.f};
    float ss[4] = {0.f, 0.f, 0.f, 0.f};
    #pragma unroll
    for (int nt = 0; nt < 8; ++nt) {
        int col = nt * 16 + arow;
        float b2 = bu2[col];
        #pragma unroll
        for (int r = 0; r < 4; ++r) {
            int node = n0 + g4 * 4 + r;
            float xv = x[(size_t)node * 128 + col];
            float g  = ga[nt][r];
            float o  = g * (u2[nt][r] + b2) + (1.f - g) * xv;
            u2[nt][r] = o;
            s[r]  += o;
            ss[r] += o * o;
        }
    }
    #pragma unroll
    for (int off = 8; off >= 1; off >>= 1) {
        #pragma unroll
        for (int r = 0; r < 4; ++r) {
            s[r]  += __shfl_xor(s[r],  off);
            ss[r] += __shfl_xor(ss[r], off);
        }
    }
    float mu[4], rstd[4];
    #pragma unroll
    for (int r = 0; r < 4; ++r) {
        mu[r] = s[r] * (1.f / 128.f);
        float var = ss[r] * (1.f / 128.f) - mu[r] * mu[r];
        rstd[r] = rsqrtf(var + 1e-5f);
    }
    #pragma unroll
    for (int nt = 0; nt < 8; ++nt) {
        int col = nt * 16 + arow;
        float gm = gamma[col], bt = beta[col];
        #pragma unroll
        for (int r = 0; r < 4; ++r) {
            int node = n0 + g4 * 4 + r;
            if (node < N)
                out[(size_t)node * 128 + col] = (u2[nt][r] - mu[r]) * rstd[r] * gm + bt;
        }
    }
}

extern "C" void kernel_launch(void* const* d_in, const int* in_sizes, int n_in,
                              void* d_out, int out_size, void* d_ws, size_t ws_size,
                              hipStream_t stream)
{
    const float* x    = (const float*)d_in[0];
    const int*   ei   = (const int*)  d_in[1];
    const float* ea   = (const float*)d_in[2];
    const float* Wm1  = (const float*)d_in[3];
    const float* bm1  = (const float*)d_in[4];
    const float* Wm2  = (const float*)d_in[5];
    const float* bm2  = (const float*)d_in[6];
    const float* Wg   = (const float*)d_in[7];
    const float* bg   = (const float*)d_in[8];
    const float* Wu1  = (const float*)d_in[9];
    const float* bu1  = (const float*)d_in[10];
    const float* Wu2  = (const float*)d_in[11];
    const float* bu2  = (const float*)d_in[12];
    const float* gmma = (const float*)d_in[13];
    const float* beta = (const float*)d_in[14];
    float* out = (float*)d_out;

    const int N = in_sizes[0] / HID;
    const int E = in_sizes[1] / 2;

    // workspace carve-up
    float*          agg  = (float*)d_ws;                             // N*128 f32
    unsigned short* xb   = (unsigned short*)(agg + (size_t)N * HID); // N*128 bf16
    unsigned short* W1f  = xb + (size_t)N * HID;                     // 32768
    unsigned short* W2f  = W1f + 32768;                              // 16384
    unsigned short* WgH  = W2f + 16384;
    unsigned short* WgL  = WgH + 32768;
    unsigned short* Wu1H = WgL + 32768;
    unsigned short* Wu1L = Wu1H + 32768;
    unsigned short* Wu2H = Wu1L + 32768;
    unsigned short* Wu2L = Wu2H + 16384;

    hipMemsetAsync(agg, 0, (size_t)N * HID * sizeof(float), stream);

    int n4 = N * HID / 4;
    prep_x<<<dim3((n4 + 255) / 256), dim3(256), 0, stream>>>((const float4*)x, xb, n4);
    prep_w<<<dim3(16), dim3(256), 0, stream>>>(Wm1, W1f, 8);
    prep_w<<<dim3(8),  dim3(256), 0, stream>>>(Wm2, W2f, 4);
    prep_w_split<<<dim3(16), dim3(256), 0, stream>>>(Wg,  WgH,  WgL,  8);
    prep_w_split<<<dim3(16), dim3(256), 0, stream>>>(Wu1, Wu1H, Wu1L, 8);
    prep_w_split<<<dim3(8),  dim3(256), 0, stream>>>(Wu2, Wu2H, Wu2L, 4);

    edge_mfma<<<dim3((E + 127) / 128), dim3(256), 0, stream>>>(
        xb, ei, ea, W1f, W2f, Wm1 + 256 * HID, bm1, bm2, agg, E);

    int ntiles = (N + 15) / 16;
    node_mfma<<<dim3((ntiles + 3) / 4), dim3(256), 0, stream>>>(
        x, agg, WgH, WgL, Wu1H, Wu1L, Wu2H, Wu2L,
        bg, bu1, bu2, gmma, beta, out, N);
}